// Round 1
// baseline (220.040 us; speedup 1.0000x reference)
//
#include <hip/hip_runtime.h>

// ---------------------------------------------------------------------------
// AttentionLayer: out = softmax((xWq+bq)(xWk+bk)^T/8 + mask) (xWv+bv)
// B=4, S=2048, D=1024, H=16, Dh=64.  All-bf16 MFMA pipeline, fp32 accum.
// R15: T14 async-STAGE split in attn.  K/V staging for kt+1 is issued as
//      global->REG loads at the top of kt's compute (latency hides under
//      ~4k cyc of MFMA/exp), then ds_write'd after the end-of-compute
//      barrier (whose implicit vmcnt(0) drains them for free).  LDS stays
//      33KB => 4 blocks/CU preserved.  Swizzle algebra: pr&15 = 4*wid+pr_l
//      is i-independent, so per-lane src offsets collapse to okl/ovl + spk.
// LAWS: bound(256,4)=>spill; reuse=2=>spill; 7 scheduling variants null/neg;
//      attn floor 94.3 under old swizzle with CONSTANT 4.26M bank conflicts;
//      R14 pair-interleave killed conflicts (0) but stayed ~94 => stall is
//      exposed staging latency, not LDS.
// ---------------------------------------------------------------------------

typedef __attribute__((ext_vector_type(8))) short bf16x8;
typedef __attribute__((ext_vector_type(4))) float f32x4;
typedef __attribute__((ext_vector_type(16))) float f32x16;

#define LOG2E 1.4426950408889634f

__device__ __forceinline__ ushort f2bf(float f) {
  union { float f; unsigned int u; } x; x.f = f;
  unsigned int r = x.u + 0x7fffu + ((x.u >> 16) & 1u);   // RNE
  return (ushort)(r >> 16);
}

// async global->LDS, 16B per lane; LDS dest = wave-uniform base + lane*16
__device__ __forceinline__ void gload16(const ushort* g, ushort* l) {
  __builtin_amdgcn_global_load_lds(
      (__attribute__((address_space(1))) unsigned int*)(g),
      (__attribute__((address_space(3))) unsigned int*)(l), 16, 0, 0);
}

// ---------------------------------------------------------------------------
// prep: blocks 0..8191 = x->bf16; 8192..11263 = W transpose; 11264 = mask scan
__global__ __launch_bounds__(256) void prep(
    const float* __restrict__ x, ushort* __restrict__ xb,
    const float* __restrict__ Wq, const float* __restrict__ Wk,
    const float* __restrict__ Wv, ushort* __restrict__ WT,
    const int* __restrict__ mask, int* __restrict__ flagw) {
  __shared__ float tile[32][33];
  __shared__ int accum[64];
  const int blk = blockIdx.x, t = threadIdx.x;
  if (blk < 8192) {
    int i = blk * 256 + t;
    float4 v = ((const float4*)x)[i];
    ushort4 o;
    o.x = f2bf(v.x); o.y = f2bf(v.y); o.z = f2bf(v.z); o.w = f2bf(v.w);
    ((ushort4*)xb)[i] = o;
  } else if (blk < 11264) {
    int bb = blk - 8192;
    int z = bb >> 10, rem = bb & 1023, db = rem >> 5, nb = rem & 31;
    const float* W = (z == 0) ? Wq : ((z == 1) ? Wk : Wv);
    int tx = t & 31, ty = t >> 5;   // 32 x 8
#pragma unroll
    for (int i = 0; i < 4; i++) {
      int dl = ty + i * 8;
      tile[dl][tx] = W[(size_t)(db * 32 + dl) * 1024 + nb * 32 + tx];
    }
    __syncthreads();
#pragma unroll
    for (int i = 0; i < 4; i++) {
      int nl = ty + i * 8;
      WT[(size_t)(z * 1024 + nb * 32 + nl) * 1024 + db * 32 + tx] = f2bf(tile[tx][nl]);
    }
  } else {
    if (t < 64) accum[t] = 0;
    __syncthreads();
    int p = t >> 2, j = t & 3;          // p = b*16+kt
    int base = p * 128 + j * 32;
    int s = 0;
#pragma unroll
    for (int i = 0; i < 8; i++) {
      int4 v = *(const int4*)(mask + base + i * 4);
      s += v.x + v.y + v.z + v.w;
    }
    atomicAdd(&accum[p], s);
    __syncthreads();
    if (t < 4) {
      int w = 0;
#pragma unroll
      for (int kt = 0; kt < 16; kt++)
        if (accum[t * 16 + kt] != 128) w |= (1 << kt);
      flagw[t] = w;
    }
  }
}

// ---------------------------------------------------------------------------
// fused QKV GEMM, m97 structure + early-issue staging (R8 version, (256,2)).
// blocks 0..1023: mode0 (Q,K: M=8192 N=2048); 1024..1535: mode1 (V^T).
__global__ __launch_bounds__(256, 2) void gemm_qkv(
    const ushort* __restrict__ xb, const ushort* __restrict__ WT,
    const float* __restrict__ bq, const float* __restrict__ bk,
    const float* __restrict__ bv, ushort* __restrict__ Qg,
    ushort* __restrict__ Kg, ushort* __restrict__ VTg) {
  __shared__ __align__(16) ushort As[128 * 64];
  __shared__ __align__(16) ushort Bs[128 * 64];
  const int t = threadIdx.x, wid = t >> 6, lane = t & 63;
  const int blk = blockIdx.x;
  int mode, mb, nb;
  const ushort *A, *B;
  if (blk < 1024) {
    mode = 0;
    int lin2 = (blk & 7) * 128 + (blk >> 3);   // XCD owns 8 mb-panels
    nb = lin2 & 15; mb = lin2 >> 4;
    A = xb; B = WT;
  } else {
    mode = 1;
    int l = blk - 1024;
    int lin2 = (l & 7) * 64 + (l >> 3);        // XCD owns 8 nb-panels
    mb = lin2 & 7; nb = lin2 >> 3;
    A = WT + (size_t)2048 * 1024; B = xb;
  }
  const ushort* Ab = A + (size_t)mb * 128 * 1024;
  const ushort* Bb = B + (size_t)nb * 128 * 1024;
  const int wr = wid >> 1, wc = wid & 1;

  f32x4 acc[4][4] = {};

  const int srow = lane >> 3;              // 0..7 row-in-8
  const int schunk = (lane & 7) ^ srow;    // pre-swizzled source chunk

  // prologue: issue stage(0)
#pragma unroll
  for (int i = 0; i < 4; i++) {
    int blki = i * 4 + wid;
    int row = blki * 8 + srow;
    int ldso = __builtin_amdgcn_readfirstlane(blki * 512);
    gload16(Ab + (size_t)row * 1024 + schunk * 8, As + ldso);
    gload16(Bb + (size_t)row * 1024 + schunk * 8, Bs + ldso);
  }

  for (int kt = 0; kt < 16; ++kt) {
    __syncthreads();                       // (1) stage(kt) arrived

    bf16x8 af[2][4], bf[2][4];
#pragma unroll
    for (int ks = 0; ks < 2; ks++) {
#pragma unroll
      for (int m = 0; m < 4; m++) {
        int row = wr * 64 + m * 16 + (lane & 15);
        int slot = (ks * 4 + (lane >> 4)) ^ (row & 7);
        af[ks][m] = *(const bf16x8*)(As + row * 64 + slot * 8);
      }
#pragma unroll
      for (int n = 0; n < 4; n++) {
        int row = wc * 64 + n * 16 + (lane & 15);
        int slot = (ks * 4 + (lane >> 4)) ^ (row & 7);
        bf[ks][n] = *(const bf16x8*)(Bs + row * 64 + slot * 8);
      }
    }
    __syncthreads();                       // (2) all fragment reads in regs

    if (kt < 15) {
      const int kof = (kt + 1) * 64 + schunk * 8;
#pragma unroll
      for (int i = 0; i < 4; i++) {
        int blki = i * 4 + wid;
        int row = blki * 8 + srow;
        int ldso = __builtin_amdgcn_readfirstlane(blki * 512);
        gload16(Ab + (size_t)row * 1024 + kof, As + ldso);
        gload16(Bb + (size_t)row * 1024 + kof, Bs + ldso);
      }
    }

#pragma unroll
    for (int ks = 0; ks < 2; ks++)
#pragma unroll
      for (int m = 0; m < 4; m++)
#pragma unroll
        for (int n = 0; n < 4; n++)
          acc[m][n] = __builtin_amdgcn_mfma_f32_16x16x32_bf16(
              af[ks][m], bf[ks][n], acc[m][n], 0, 0, 0);
  }

  // epilogue
#pragma unroll
  for (int m = 0; m < 4; m++) {
#pragma unroll
    for (int n = 0; n < 4; n++) {
      if (mode == 0) {
        int col = nb * 128 + wc * 64 + n * 16 + (lane & 15);  // n: [Q|K] 0..2047
        int wq = col >> 10;                                   // 0=Q 1=K
        float bs = wq ? bk[col & 1023] : bq[col & 1023];
        float scale = wq ? 1.0f : (0.125f * LOG2E);           // fold log2e into Q
        ushort* dst = wq ? Kg : Qg;
        int h = (col >> 6) & 15, d = col & 63;
#pragma unroll
        for (int r = 0; r < 4; r++) {
          int row = mb * 128 + wr * 64 + m * 16 + (lane >> 4) * 4 + r;  // b*2048+s
          int b = row >> 11, s = row & 2047;
          float v = (acc[m][n][r] + bs) * scale;
          dst[((size_t)((b << 4) + h) * 2048 + s) * 64 + d] = f2bf(v);
        }
      } else {
        int col = nb * 128 + wc * 64 + n * 16 + (lane & 15);  // m-index: b*2048+s
        int b = col >> 11, s = col & 2047;
#pragma unroll
        for (int r = 0; r < 4; r++) {
          int p = mb * 128 + wr * 64 + m * 16 + (lane >> 4) * 4 + r;  // h*64+d
          float v = acc[m][n][r] + bv[p];
          int h = p >> 6, d = p & 63;
          VTg[((size_t)((b << 4) + h) * 64 + d) * 2048 + s] = f2bf(v);
        }
      }
    }
  }
}

// ---------------------------------------------------------------------------
// Flash attention (R15 body): swapped-operand 32x32 MFMA, single-buffer LDS,
// T14 async staging: global->reg loads for kt+1 issued at top of kt compute,
// ds_write after the end-of-compute barrier (implicit vmcnt(0) drains them).
// K/Q pair-interleave LDS mapping unchanged (conflict-free, R14).
__global__ __launch_bounds__(256, 3) void attn_kernel(
    const ushort* __restrict__ Qg, const ushort* __restrict__ Kg,
    const ushort* __restrict__ VTg, const int* __restrict__ mask,
    const int* __restrict__ flagw, float* __restrict__ out) {
  __shared__ __align__(16) ushort Ks[128 * 64];   // 16KB; 64 phys rows x 256B
  __shared__ __align__(16) ushort Vs[64 * 128];   // 16KB; rows=d, 4-bit swizzle
  __shared__ float maddv[128];

  const int t = threadIdx.x, wid = t >> 6, lane = t & 63;
  const int l31 = lane & 31, hi = lane >> 5;
  const int lin = blockIdx.x;
  const int lin2 = (lin & 7) * 128 + (lin >> 3);   // bijective XCD chunking
  const int qb = lin2 & 15, bh = lin2 >> 4;
  const int b = bh >> 4, h = bh & 15;
  const ushort* Qbh = Qg + ((size_t)bh * 2048 + qb * 128) * 64;
  const ushort* Kbh = Kg + (size_t)bh * 2048 * 64;
  const ushort* Vbh = VTg + (size_t)bh * 64 * 2048;

  // ---- staging lane constants ----
  // pr = 16*i + 4*wid + pr_l  =>  pr&15 = 4*wid + pr_l  (i-independent!)
  // so the pair-interleave source swizzle collapses to one per-lane const.
  const int pr_l = lane >> 4;                 // 0..3 within issue
  const int s_l = lane & 15;
  const int spk = s_l ^ (4 * wid + pr_l);     // shared by K and V paths
  // K src (ushort offs): kt*8192 + 2048*i + okl
  const int okl = 512 * wid + 128 * pr_l + (spk >> 3) * 64 + (spk & 7) * 8;
  // V src (ushort offs): 32768*i + kt*128 + ovl
  const int ovl = 8192 * wid + 2048 * pr_l + spk * 8;
  // LDS dst (ushort offs): 2048*i + lwr   (linear, matches gload_lds layout)
  const int lwr = 512 * wid + lane * 8;

  // ---- fragment-read lane constants ----
  const int prq = l31 >> 1;                   // phys row within 16-row group
  const int halfq = l31 & 1;
  const int pr14 = prq & 15;

  // ---- prologue: stage Q tile [128][64] into Ks (pair-interleaved) ----
#pragma unroll
  for (int i = 0; i < 4; i++) {
    int blki = i * 4 + wid;
    int ldso = __builtin_amdgcn_readfirstlane(blki * 512);
    int pr = blki * 4 + pr_l;
    int sp = s_l ^ (pr & 15);
    gload16(Qbh + (size_t)(2 * pr + (sp >> 3)) * 64 + (sp & 7) * 8, Ks + ldso);
  }
  // issue K(0)/V(0) -> regs (in flight across the Q barrier)
  bf16x8 kst[4], vst[4];
#pragma unroll
  for (int i = 0; i < 4; i++)
    kst[i] = *(const bf16x8*)(Kbh + 2048 * i + okl);
#pragma unroll
  for (int i = 0; i < 4; i++)
    vst[i] = *(const bf16x8*)(Vbh + 32768 * i + ovl);
  const int fb = flagw[b];            // per-tile mask bits (uniform)
  __syncthreads();                    // Q staged; kst/vst drained too
  bf16x8 qf[4];
  {
    const ushort* qbase = Ks + (wid * 16 + prq) * 128;   // phys row *256B
#pragma unroll
    for (int ds = 0; ds < 4; ds++) {
      int slot = ((ds * 2 + hi) | (halfq << 3)) ^ pr14;
      qf[ds] = *(const bf16x8*)(qbase + slot * 8);
    }
  }
  __syncthreads();                    // qf reads done before Ks restage
#pragma unroll
  for (int i = 0; i < 4; i++) *(bf16x8*)(Ks + 2048 * i + lwr) = kst[i];
#pragma unroll
  for (int i = 0; i < 4; i++) *(bf16x8*)(Vs + 2048 * i + lwr) = vst[i];
  if (((fb >> 0) & 1) && t < 128)
    maddv[t] = (1.0f - (float)mask[b * 2048 + t]) * (-10000.0f * LOG2E);

  const f32x16 fzero = {};
  f32x16 cacc[2] = {};
  float l0 = 0.f, l1 = 0.f, l2 = 0.f, l3 = 0.f;  // persistent psum chains

  for (int kt = 0; kt < 16; ++kt) {
    __syncthreads();                  // (A) tile kt visible in LDS

    // ---- issue stage(kt+1) -> regs; latency hides under kt's compute ----
    if (kt < 15) {
#pragma unroll
      for (int i = 0; i < 4; i++)
        kst[i] = *(const bf16x8*)(Kbh + (size_t)(kt + 1) * 8192 + 2048 * i + okl);
#pragma unroll
      for (int i = 0; i < 4; i++)
        vst[i] = *(const bf16x8*)(Vbh + 32768 * i + (kt + 1) * 128 + ovl);
    }
    const bool msk = ((fb >> kt) & 1) != 0;

    // ---- per-kb fused: QK (4 MFMA) -> exp2 -> pack -> PV (4 MFMA) ----
#pragma unroll
    for (int kb = 0; kb < 4; kb++) {
      const ushort* krow = Ks + (kb * 16 + prq) * 128;   // phys row base
      __builtin_amdgcn_s_setprio(1);
      bf16x8 kf0 = *(const bf16x8*)(krow + (((0 + hi) | (halfq << 3)) ^ pr14) * 8);
      f32x16 a = __builtin_amdgcn_mfma_f32_32x32x16_bf16(kf0, qf[0], fzero, 0, 0, 0);
      bf16x8 kf1 = *(const bf16x8*)(krow + (((2 + hi) | (halfq << 3)) ^ pr14) * 8);
      a = __builtin_amdgcn_mfma_f32_32x32x16_bf16(kf1, qf[1], a, 0, 0, 0);
      bf16x8 kf2 = *(const bf16x8*)(krow + (((4 + hi) | (halfq << 3)) ^ pr14) * 8);
      a = __builtin_amdgcn_mfma_f32_32x32x16_bf16(kf2, qf[2], a, 0, 0, 0);
      bf16x8 kf3 = *(const bf16x8*)(krow + (((6 + hi) | (halfq << 3)) ^ pr14) * 8);
      a = __builtin_amdgcn_mfma_f32_32x32x16_bf16(kf3, qf[3], a, 0, 0, 0);
      __builtin_amdgcn_s_setprio(0);

      if (msk) {
#pragma unroll
        for (int qd = 0; qd < 4; qd++) {
          f32x4 ma = *(const f32x4*)(maddv + kb * 32 + qd * 8 + hi * 4);
#pragma unroll
          for (int rr = 0; rr < 4; rr++) a[qd * 4 + rr] += ma[rr];
        }
      }

#pragma unroll
      for (int w2 = 0; w2 < 2; w2++) {
        const int o = w2 * 8;
        float e0 = __builtin_amdgcn_exp2f(a[o + 0]);
        float e1 = __builtin_amdgcn_exp2f(a[o + 1]);
        float e2 = __builtin_amdgcn_exp2f(a[o + 2]);
        float e3 = __builtin_amdgcn_exp2f(a[o + 3]);
        float e4 = __builtin_amdgcn_exp2f(a[o + 4]);
        float e5 = __builtin_amdgcn_exp2f(a[o + 5]);
        float e6 = __builtin_amdgcn_exp2f(a[o + 6]);
        float e7 = __builtin_amdgcn_exp2f(a[o + 7]);
        l0 += e0; l1 += e1; l2 += e2; l3 += e3;
        l0 += e4; l1 += e5; l2 += e6; l3 += e7;
        unsigned a0, a1, b0, b1;
        asm("v_cvt_pk_bf16_f32 %0, %1, %2" : "=v"(a0) : "v"(e0), "v"(e1));
        asm("v_cvt_pk_bf16_f32 %0, %1, %2" : "=v"(a1) : "v"(e2), "v"(e3));
        asm("v_cvt_pk_bf16_f32 %0, %1, %2" : "=v"(b0) : "v"(e4), "v"(e5));
        asm("v_cvt_pk_bf16_f32 %0, %1, %2" : "=v"(b1) : "v"(e6), "v"(e7));
        asm("v_permlane32_swap_b32 %0, %1" : "+v"(a0), "+v"(b0));
        asm("v_permlane32_swap_b32 %0, %1" : "+v"(a1), "+v"(b1));
        union { unsigned u[4]; bf16x8 v8; } pu;
        pu.u[0] = a0; pu.u[1] = a1; pu.u[2] = b0; pu.u[3] = b1;
        bf16x8 pf = pu.v8;
        int w = kb * 2 + w2;
        __builtin_amdgcn_s_setprio(1);
#pragma unroll
        for (int df = 0; df < 2; df++) {
          int d = df * 32 + l31;
          int c = (w * 2 + hi) ^ (d & 15);
          bf16x8 vf = *(const bf16x8*)(Vs + d * 128 + c * 8);
          cacc[df] = __builtin_amdgcn_mfma_f32_32x32x16_bf16(vf, pf, cacc[df], 0, 0, 0);
        }
        __builtin_amdgcn_s_setprio(0);
      }
    }

    // ---- write-late: barrier drains LDS reads AND the in-flight vmcnt ----
    if (kt < 15) {
      __syncthreads();                // (B)
#pragma unroll
      for (int i = 0; i < 4; i++) *(bf16x8*)(Ks + 2048 * i + lwr) = kst[i];
#pragma unroll
      for (int i = 0; i < 4; i++) *(bf16x8*)(Vs + 2048 * i + lwr) = vst[i];
      if (((fb >> (kt + 1)) & 1) && t < 128)
        maddv[t] = (1.0f - (float)mask[b * 2048 + (kt + 1) * 128 + t]) * (-10000.0f * LOG2E);
    }
  }

  // ---- epilogue: l = in-lane chains + cross-hi partner; ctx^T / l ----
  float lrun = (l0 + l1) + (l2 + l3);
  lrun += __shfl_xor(lrun, 32);
  float linv = 1.0f / lrun;
  int qg = qb * 128 + wid * 32 + l31;
  float* op = out + ((size_t)(b * 2048 + qg)) * 1024 + h * 64;
#pragma unroll
  for (int df = 0; df < 2; df++)
#pragma unroll
    for (int qd = 0; qd < 4; qd++) {
      f32x4 v;
      v[0] = cacc[df][qd * 4 + 0] * linv;
      v[1] = cacc[df][qd * 4 + 1] * linv;
      v[2] = cacc[df][qd * 4 + 2] * linv;
      v[3] = cacc[df][qd * 4 + 3] * linv;
      *(f32x4*)(op + df * 32 + qd * 8 + hi * 4) = v;
    }
}

// ---------------------------------------------------------------------------
extern "C" void kernel_launch(void* const* d_in, const int* in_sizes, int n_in,
                              void* d_out, int out_size, void* d_ws, size_t ws_size,
                              hipStream_t stream) {
  const float* x  = (const float*)d_in[0];
  const int* mask = (const int*)d_in[1];
  const float* Wq = (const float*)d_in[2];
  const float* bq = (const float*)d_in[3];
  const float* Wk = (const float*)d_in[4];
  const float* bk = (const float*)d_in[5];
  const float* Wv = (const float*)d_in[6];
  const float* bv = (const float*)d_in[7];
  float* out = (float*)d_out;

  char* ws = (char*)d_ws;
  ushort* xb  = (ushort*)(ws);                                  // 16 MB
  ushort* WT  = (ushort*)(ws + (size_t)16777216);               // 6 MB
  ushort* Qg  = (ushort*)(ws + (size_t)23068672);               // 16 MB
  ushort* Kg  = (ushort*)(ws + (size_t)39845888);               // 16 MB
  ushort* VTg = (ushort*)(ws + (size_t)56623104);               // 16 MB
  int*    flg = (int*)(ws + (size_t)73400320);                  // 16 B

  prep<<<dim3(11265), dim3(256), 0, stream>>>(x, xb, Wq, Wk, Wv, WT, mask, flg);
  gemm_qkv<<<dim3(1536), dim3(256), 0, stream>>>(xb, WT, bq, bk, bv, Qg, Kg, VTg);
  attn_kernel<<<dim3(1024), dim3(256), 0, stream>>>(Qg, Kg, VTg, mask, flg, out);
}

// Round 2
// 157.828 us; speedup vs baseline: 1.3942x; 1.3942x over previous
//
#include <hip/hip_runtime.h>

// ---------------------------------------------------------------------------
// AttentionLayer: out = softmax((xWq+bq)(xWk+bk)^T/8 + mask) (xWv+bv)
// B=4, S=2048, D=1024, H=16, Dh=64.  All-bf16 MFMA pipeline, fp32 accum.
// R16: LDS DOUBLE-BUFFER staging in attn (gload_lds, no registers).
//      Per kt: issue stage(kt+1)->buf^1 FIRST, compute kt from buf, ONE
//      barrier at end (implicit vmcnt(0) drains loads that flew under the
//      whole compute phase).  LDS 65KB => 2 blocks/CU (measured occupancy
//      was already ~2 blocks, so no loss).  Barriers/iter: 2 -> 1.
// LAWS: bound(256,4)=>spill; reuse=2=>spill; 7 scheduling variants null/neg;
//      attn floor 94.3 under old swizzle with CONSTANT 4.26M bank conflicts;
//      R14 pair-interleave killed conflicts (0) but stayed ~94;
//      R15 reg-staging K/V (8x bf16x8 across barriers) SPILLS (VGPR pinned
//      84, WRITE_SIZE +21MB scratch, attn 94->165).  Never reg-stage here.
// ---------------------------------------------------------------------------

typedef __attribute__((ext_vector_type(8))) short bf16x8;
typedef __attribute__((ext_vector_type(4))) float f32x4;
typedef __attribute__((ext_vector_type(16))) float f32x16;

#define LOG2E 1.4426950408889634f

__device__ __forceinline__ ushort f2bf(float f) {
  union { float f; unsigned int u; } x; x.f = f;
  unsigned int r = x.u + 0x7fffu + ((x.u >> 16) & 1u);   // RNE
  return (ushort)(r >> 16);
}

// async global->LDS, 16B per lane; LDS dest = wave-uniform base + lane*16
__device__ __forceinline__ void gload16(const ushort* g, ushort* l) {
  __builtin_amdgcn_global_load_lds(
      (__attribute__((address_space(1))) unsigned int*)(g),
      (__attribute__((address_space(3))) unsigned int*)(l), 16, 0, 0);
}

// ---------------------------------------------------------------------------
// prep: blocks 0..8191 = x->bf16; 8192..11263 = W transpose; 11264 = mask scan
__global__ __launch_bounds__(256) void prep(
    const float* __restrict__ x, ushort* __restrict__ xb,
    const float* __restrict__ Wq, const float* __restrict__ Wk,
    const float* __restrict__ Wv, ushort* __restrict__ WT,
    const int* __restrict__ mask, int* __restrict__ flagw) {
  __shared__ float tile[32][33];
  __shared__ int accum[64];
  const int blk = blockIdx.x, t = threadIdx.x;
  if (blk < 8192) {
    int i = blk * 256 + t;
    float4 v = ((const float4*)x)[i];
    ushort4 o;
    o.x = f2bf(v.x); o.y = f2bf(v.y); o.z = f2bf(v.z); o.w = f2bf(v.w);
    ((ushort4*)xb)[i] = o;
  } else if (blk < 11264) {
    int bb = blk - 8192;
    int z = bb >> 10, rem = bb & 1023, db = rem >> 5, nb = rem & 31;
    const float* W = (z == 0) ? Wq : ((z == 1) ? Wk : Wv);
    int tx = t & 31, ty = t >> 5;   // 32 x 8
#pragma unroll
    for (int i = 0; i < 4; i++) {
      int dl = ty + i * 8;
      tile[dl][tx] = W[(size_t)(db * 32 + dl) * 1024 + nb * 32 + tx];
    }
    __syncthreads();
#pragma unroll
    for (int i = 0; i < 4; i++) {
      int nl = ty + i * 8;
      WT[(size_t)(z * 1024 + nb * 32 + nl) * 1024 + db * 32 + tx] = f2bf(tile[tx][nl]);
    }
  } else {
    if (t < 64) accum[t] = 0;
    __syncthreads();
    int p = t >> 2, j = t & 3;          // p = b*16+kt
    int base = p * 128 + j * 32;
    int s = 0;
#pragma unroll
    for (int i = 0; i < 8; i++) {
      int4 v = *(const int4*)(mask + base + i * 4);
      s += v.x + v.y + v.z + v.w;
    }
    atomicAdd(&accum[p], s);
    __syncthreads();
    if (t < 4) {
      int w = 0;
#pragma unroll
      for (int kt = 0; kt < 16; kt++)
        if (accum[t * 16 + kt] != 128) w |= (1 << kt);
      flagw[t] = w;
    }
  }
}

// ---------------------------------------------------------------------------
// fused QKV GEMM, m97 structure + early-issue staging (R8 version, (256,2)).
// blocks 0..1023: mode0 (Q,K: M=8192 N=2048); 1024..1535: mode1 (V^T).
__global__ __launch_bounds__(256, 2) void gemm_qkv(
    const ushort* __restrict__ xb, const ushort* __restrict__ WT,
    const float* __restrict__ bq, const float* __restrict__ bk,
    const float* __restrict__ bv, ushort* __restrict__ Qg,
    ushort* __restrict__ Kg, ushort* __restrict__ VTg) {
  __shared__ __align__(16) ushort As[128 * 64];
  __shared__ __align__(16) ushort Bs[128 * 64];
  const int t = threadIdx.x, wid = t >> 6, lane = t & 63;
  const int blk = blockIdx.x;
  int mode, mb, nb;
  const ushort *A, *B;
  if (blk < 1024) {
    mode = 0;
    int lin2 = (blk & 7) * 128 + (blk >> 3);   // XCD owns 8 mb-panels
    nb = lin2 & 15; mb = lin2 >> 4;
    A = xb; B = WT;
  } else {
    mode = 1;
    int l = blk - 1024;
    int lin2 = (l & 7) * 64 + (l >> 3);        // XCD owns 8 nb-panels
    mb = lin2 & 7; nb = lin2 >> 3;
    A = WT + (size_t)2048 * 1024; B = xb;
  }
  const ushort* Ab = A + (size_t)mb * 128 * 1024;
  const ushort* Bb = B + (size_t)nb * 128 * 1024;
  const int wr = wid >> 1, wc = wid & 1;

  f32x4 acc[4][4] = {};

  const int srow = lane >> 3;              // 0..7 row-in-8
  const int schunk = (lane & 7) ^ srow;    // pre-swizzled source chunk

  // prologue: issue stage(0)
#pragma unroll
  for (int i = 0; i < 4; i++) {
    int blki = i * 4 + wid;
    int row = blki * 8 + srow;
    int ldso = __builtin_amdgcn_readfirstlane(blki * 512);
    gload16(Ab + (size_t)row * 1024 + schunk * 8, As + ldso);
    gload16(Bb + (size_t)row * 1024 + schunk * 8, Bs + ldso);
  }

  for (int kt = 0; kt < 16; ++kt) {
    __syncthreads();                       // (1) stage(kt) arrived

    bf16x8 af[2][4], bf[2][4];
#pragma unroll
    for (int ks = 0; ks < 2; ks++) {
#pragma unroll
      for (int m = 0; m < 4; m++) {
        int row = wr * 64 + m * 16 + (lane & 15);
        int slot = (ks * 4 + (lane >> 4)) ^ (row & 7);
        af[ks][m] = *(const bf16x8*)(As + row * 64 + slot * 8);
      }
#pragma unroll
      for (int n = 0; n < 4; n++) {
        int row = wc * 64 + n * 16 + (lane & 15);
        int slot = (ks * 4 + (lane >> 4)) ^ (row & 7);
        bf[ks][n] = *(const bf16x8*)(Bs + row * 64 + slot * 8);
      }
    }
    __syncthreads();                       // (2) all fragment reads in regs

    if (kt < 15) {
      const int kof = (kt + 1) * 64 + schunk * 8;
#pragma unroll
      for (int i = 0; i < 4; i++) {
        int blki = i * 4 + wid;
        int row = blki * 8 + srow;
        int ldso = __builtin_amdgcn_readfirstlane(blki * 512);
        gload16(Ab + (size_t)row * 1024 + kof, As + ldso);
        gload16(Bb + (size_t)row * 1024 + kof, Bs + ldso);
      }
    }

#pragma unroll
    for (int ks = 0; ks < 2; ks++)
#pragma unroll
      for (int m = 0; m < 4; m++)
#pragma unroll
        for (int n = 0; n < 4; n++)
          acc[m][n] = __builtin_amdgcn_mfma_f32_16x16x32_bf16(
              af[ks][m], bf[ks][n], acc[m][n], 0, 0, 0);
  }

  // epilogue
#pragma unroll
  for (int m = 0; m < 4; m++) {
#pragma unroll
    for (int n = 0; n < 4; n++) {
      if (mode == 0) {
        int col = nb * 128 + wc * 64 + n * 16 + (lane & 15);  // n: [Q|K] 0..2047
        int wq = col >> 10;                                   // 0=Q 1=K
        float bs = wq ? bk[col & 1023] : bq[col & 1023];
        float scale = wq ? 1.0f : (0.125f * LOG2E);           // fold log2e into Q
        ushort* dst = wq ? Kg : Qg;
        int h = (col >> 6) & 15, d = col & 63;
#pragma unroll
        for (int r = 0; r < 4; r++) {
          int row = mb * 128 + wr * 64 + m * 16 + (lane >> 4) * 4 + r;  // b*2048+s
          int b = row >> 11, s = row & 2047;
          float v = (acc[m][n][r] + bs) * scale;
          dst[((size_t)((b << 4) + h) * 2048 + s) * 64 + d] = f2bf(v);
        }
      } else {
        int col = nb * 128 + wc * 64 + n * 16 + (lane & 15);  // m-index: b*2048+s
        int b = col >> 11, s = col & 2047;
#pragma unroll
        for (int r = 0; r < 4; r++) {
          int p = mb * 128 + wr * 64 + m * 16 + (lane >> 4) * 4 + r;  // h*64+d
          float v = acc[m][n][r] + bv[p];
          int h = p >> 6, d = p & 63;
          VTg[((size_t)((b << 4) + h) * 64 + d) * 2048 + s] = f2bf(v);
        }
      }
    }
  }
}

// ---------------------------------------------------------------------------
// Flash attention (R16 body): swapped-operand 32x32 MFMA, DOUBLE-BUFFERED
// gload_lds staging, one barrier per kt.  Tile kt lives in buf=(kt+1)&1
// (Ks[0] doubles as Q staging in the prologue).  Stage(kt+1) is issued at
// the top of iteration kt, flies under kt's compute, and is drained by the
// single end-of-iteration barrier.  K/Q pair-interleave swizzle unchanged.
__global__ __launch_bounds__(256, 2) void attn_kernel(
    const ushort* __restrict__ Qg, const ushort* __restrict__ Kg,
    const ushort* __restrict__ VTg, const int* __restrict__ mask,
    const int* __restrict__ flagw, float* __restrict__ out) {
  __shared__ __align__(16) ushort Ks[2][128 * 64];   // 2x16KB
  __shared__ __align__(16) ushort Vs[2][64 * 128];   // 2x16KB
  __shared__ float maddv[2][128];                    // 1KB

  const int t = threadIdx.x, wid = t >> 6, lane = t & 63;
  const int l31 = lane & 31, hi = lane >> 5;
  const int lin = blockIdx.x;
  const int lin2 = (lin & 7) * 128 + (lin >> 3);   // bijective XCD chunking
  const int qb = lin2 & 15, bh = lin2 >> 4;
  const int b = bh >> 4, h = bh & 15;
  const ushort* Qbh = Qg + ((size_t)bh * 2048 + qb * 128) * 64;
  const ushort* Kbh = Kg + (size_t)bh * 2048 * 64;
  const ushort* Vbh = VTg + (size_t)bh * 64 * 2048;

  // ---- K/Q staging lane constants (pair-interleave inverse map) ----
  const int pr_l = lane >> 4;                 // 0..3 within issue
  const int s_l = lane & 15;

  // ---- fragment-read lane constants ----
  const int prq = l31 >> 1;                   // phys row within 16-row group
  const int halfq = l31 & 1;
  const int pr14 = prq & 15;

  // ---- prologue: stage Q->Ks[0], K0->Ks[1], V0->Vs[1], all in flight ----
#pragma unroll
  for (int i = 0; i < 4; i++) {
    int blki = i * 4 + wid;
    int ldso = __builtin_amdgcn_readfirstlane(blki * 512);
    int pr = blki * 4 + pr_l;
    int sp = s_l ^ (pr & 15);
    gload16(Qbh + (size_t)(2 * pr + (sp >> 3)) * 64 + (sp & 7) * 8,
            &Ks[0][0] + ldso);
    gload16(Kbh + (size_t)(2 * pr + (sp >> 3)) * 64 + (sp & 7) * 8,
            &Ks[1][0] + ldso);
    int d = blki * 4 + pr_l;
    int cvg = s_l ^ (d & 15);
    gload16(Vbh + (size_t)d * 2048 + cvg * 8, &Vs[1][0] + ldso);
  }
  const int fb = flagw[b];            // per-tile mask bits (uniform)
  if (((fb >> 0) & 1) && t < 128)
    maddv[1][t] = (1.0f - (float)mask[b * 2048 + t]) * (-10000.0f * LOG2E);
  __syncthreads();                    // Q+K0+V0 staged
  bf16x8 qf[4];
  {
    const ushort* qbase = &Ks[0][0] + (wid * 16 + prq) * 128;   // phys row *256B
#pragma unroll
    for (int ds = 0; ds < 4; ds++) {
      int slot = ((ds * 2 + hi) | (halfq << 3)) ^ pr14;
      qf[ds] = *(const bf16x8*)(qbase + slot * 8);
    }
  }
  __syncthreads();                    // qf reads done before Ks[0] restage

  const f32x16 fzero = {};
  f32x16 cacc[2] = {};
  float l0 = 0.f, l1 = 0.f, l2 = 0.f, l3 = 0.f;  // persistent psum chains

  for (int kt = 0; kt < 16; ++kt) {
    const int bufc = (kt + 1) & 1;    // tile kt resides here
    const int bufn = bufc ^ 1;        // stage target for kt+1

    // ---- issue stage(kt+1) -> buf^1; flies under kt's whole compute ----
    if (kt < 15) {
#pragma unroll
      for (int i = 0; i < 4; i++) {
        int blki = i * 4 + wid;
        int ldso = __builtin_amdgcn_readfirstlane(blki * 512);
        int pr = blki * 4 + pr_l;
        int sp = s_l ^ (pr & 15);
        gload16(Kbh + (size_t)((kt + 1) * 128 + 2 * pr + (sp >> 3)) * 64 + (sp & 7) * 8,
                &Ks[bufn][0] + ldso);
        int d = blki * 4 + pr_l;
        int cvg = s_l ^ (d & 15);
        gload16(Vbh + (size_t)d * 2048 + (kt + 1) * 128 + cvg * 8,
                &Vs[bufn][0] + ldso);
      }
      if (((fb >> (kt + 1)) & 1) && t < 128)
        maddv[bufn][t] =
            (1.0f - (float)mask[b * 2048 + (kt + 1) * 128 + t]) * (-10000.0f * LOG2E);
    }
    const bool msk = ((fb >> kt) & 1) != 0;
    const ushort* Ksb = &Ks[bufc][0];
    const ushort* Vsb = &Vs[bufc][0];

    // ---- per-kb fused: QK (4 MFMA) -> exp2 -> pack -> PV (4 MFMA) ----
#pragma unroll
    for (int kb = 0; kb < 4; kb++) {
      const ushort* krow = Ksb + (kb * 16 + prq) * 128;   // phys row base
      __builtin_amdgcn_s_setprio(1);
      bf16x8 kf0 = *(const bf16x8*)(krow + (((0 + hi) | (halfq << 3)) ^ pr14) * 8);
      f32x16 a = __builtin_amdgcn_mfma_f32_32x32x16_bf16(kf0, qf[0], fzero, 0, 0, 0);
      bf16x8 kf1 = *(const bf16x8*)(krow + (((2 + hi) | (halfq << 3)) ^ pr14) * 8);
      a = __builtin_amdgcn_mfma_f32_32x32x16_bf16(kf1, qf[1], a, 0, 0, 0);
      bf16x8 kf2 = *(const bf16x8*)(krow + (((4 + hi) | (halfq << 3)) ^ pr14) * 8);
      a = __builtin_amdgcn_mfma_f32_32x32x16_bf16(kf2, qf[2], a, 0, 0, 0);
      bf16x8 kf3 = *(const bf16x8*)(krow + (((6 + hi) | (halfq << 3)) ^ pr14) * 8);
      a = __builtin_amdgcn_mfma_f32_32x32x16_bf16(kf3, qf[3], a, 0, 0, 0);
      __builtin_amdgcn_s_setprio(0);

      if (msk) {
#pragma unroll
        for (int qd = 0; qd < 4; qd++) {
          f32x4 ma = *(const f32x4*)(&maddv[bufc][0] + kb * 32 + qd * 8 + hi * 4);
#pragma unroll
          for (int rr = 0; rr < 4; rr++) a[qd * 4 + rr] += ma[rr];
        }
      }

#pragma unroll
      for (int w2 = 0; w2 < 2; w2++) {
        const int o = w2 * 8;
        float e0 = __builtin_amdgcn_exp2f(a[o + 0]);
        float e1 = __builtin_amdgcn_exp2f(a[o + 1]);
        float e2 = __builtin_amdgcn_exp2f(a[o + 2]);
        float e3 = __builtin_amdgcn_exp2f(a[o + 3]);
        float e4 = __builtin_amdgcn_exp2f(a[o + 4]);
        float e5 = __builtin_amdgcn_exp2f(a[o + 5]);
        float e6 = __builtin_amdgcn_exp2f(a[o + 6]);
        float e7 = __builtin_amdgcn_exp2f(a[o + 7]);
        l0 += e0; l1 += e1; l2 += e2; l3 += e3;
        l0 += e4; l1 += e5; l2 += e6; l3 += e7;
        unsigned a0, a1, b0, b1;
        asm("v_cvt_pk_bf16_f32 %0, %1, %2" : "=v"(a0) : "v"(e0), "v"(e1));
        asm("v_cvt_pk_bf16_f32 %0, %1, %2" : "=v"(a1) : "v"(e2), "v"(e3));
        asm("v_cvt_pk_bf16_f32 %0, %1, %2" : "=v"(b0) : "v"(e4), "v"(e5));
        asm("v_cvt_pk_bf16_f32 %0, %1, %2" : "=v"(b1) : "v"(e6), "v"(e7));
        asm("v_permlane32_swap_b32 %0, %1" : "+v"(a0), "+v"(b0));
        asm("v_permlane32_swap_b32 %0, %1" : "+v"(a1), "+v"(b1));
        union { unsigned u[4]; bf16x8 v8; } pu;
        pu.u[0] = a0; pu.u[1] = a1; pu.u[2] = b0; pu.u[3] = b1;
        bf16x8 pf = pu.v8;
        int w = kb * 2 + w2;
        __builtin_amdgcn_s_setprio(1);
#pragma unroll
        for (int df = 0; df < 2; df++) {
          int d = df * 32 + l31;
          int c = (w * 2 + hi) ^ (d & 15);
          bf16x8 vf = *(const bf16x8*)(Vsb + d * 128 + c * 8);
          cacc[df] = __builtin_amdgcn_mfma_f32_32x32x16_bf16(vf, pf, cacc[df], 0, 0, 0);
        }
        __builtin_amdgcn_s_setprio(0);
      }
    }

    // ---- single barrier: drains stage(kt+1) vmcnt AND fences LDS reads ----
    if (kt < 15) __syncthreads();
  }

  // ---- epilogue: l = in-lane chains + cross-hi partner; ctx^T / l ----
  float lrun = (l0 + l1) + (l2 + l3);
  lrun += __shfl_xor(lrun, 32);
  float linv = 1.0f / lrun;
  int qg = qb * 128 + wid * 32 + l31;
  float* op = out + ((size_t)(b * 2048 + qg)) * 1024 + h * 64;
#pragma unroll
  for (int df = 0; df < 2; df++)
#pragma unroll
    for (int qd = 0; qd < 4; qd++) {
      f32x4 v;
      v[0] = cacc[df][qd * 4 + 0] * linv;
      v[1] = cacc[df][qd * 4 + 1] * linv;
      v[2] = cacc[df][qd * 4 + 2] * linv;
      v[3] = cacc[df][qd * 4 + 3] * linv;
      *(f32x4*)(op + df * 32 + qd * 8 + hi * 4) = v;
    }
}

// ---------------------------------------------------------------------------
extern "C" void kernel_launch(void* const* d_in, const int* in_sizes, int n_in,
                              void* d_out, int out_size, void* d_ws, size_t ws_size,
                              hipStream_t stream) {
  const float* x  = (const float*)d_in[0];
  const int* mask = (const int*)d_in[1];
  const float* Wq = (const float*)d_in[2];
  const float* bq = (const float*)d_in[3];
  const float* Wk = (const float*)d_in[4];
  const float* bk = (const float*)d_in[5];
  const float* Wv = (const float*)d_in[6];
  const float* bv = (const float*)d_in[7];
  float* out = (float*)d_out;

  char* ws = (char*)d_ws;
  ushort* xb  = (ushort*)(ws);                                  // 16 MB
  ushort* WT  = (ushort*)(ws + (size_t)16777216);               // 6 MB
  ushort* Qg  = (ushort*)(ws + (size_t)23068672);               // 16 MB
  ushort* Kg  = (ushort*)(ws + (size_t)39845888);               // 16 MB
  ushort* VTg = (ushort*)(ws + (size_t)56623104);               // 16 MB
  int*    flg = (int*)(ws + (size_t)73400320);                  // 16 B

  prep<<<dim3(11265), dim3(256), 0, stream>>>(x, xb, Wq, Wk, Wv, WT, mask, flg);
  gemm_qkv<<<dim3(1536), dim3(256), 0, stream>>>(xb, WT, bq, bk, bv, Qg, Kg, VTg);
  attn_kernel<<<dim3(1024), dim3(256), 0, stream>>>(Qg, Kg, VTg, mask, flg, out);
}

// Round 3
// 155.039 us; speedup vs baseline: 1.4193x; 1.0180x over previous
//
#include <hip/hip_runtime.h>

// ---------------------------------------------------------------------------
// AttentionLayer: out = softmax((xWq+bq)(xWk+bk)^T/8 + mask) (xWv+bv)
// B=4, S=2048, D=1024, H=16, Dh=64.  All-bf16 MFMA pipeline, fp32 accum.
// R17: T15 att[2] pipeline in attn.  Two P-tiles (aA/aB) live: QK(kb+1)
//      MFMAs overlap softmax-finish(kb) VALU.  launch_bounds (256,2) to
//      grant the +16 regs (occupancy stays in the 129-256 band = 2
//      waves/SIMD either way => zero occupancy cost).  Single-buffer
//      staging (R14 form); qf loaded direct from global (no Q prologue).
// LAWS: bound(256,4)=>spill (total<=128 unreachable); reuse=2=>spill;
//      7 barrier/waitcnt scheduling variants null/neg;
//      R14 floor 94.3 with 0 bank conflicts;
//      R15 reg-staging K/V across barriers SPILLS (VGPR pinned 84 = arch
//      count at the (256,3) 170-total cap; ~86 AGPRs hidden) -> total
//      ~170 -> 2 waves/SIMD band -> 8 waves/CU regardless of LDS;
//      R16 LDS dbuf 65KB/1-barrier = -5% (staging exposure was never it).
//      => occupancy is capped structurally; per-wave ILP is the lever.
// ---------------------------------------------------------------------------

typedef __attribute__((ext_vector_type(8))) short bf16x8;
typedef __attribute__((ext_vector_type(4))) float f32x4;
typedef __attribute__((ext_vector_type(16))) float f32x16;

#define LOG2E 1.4426950408889634f

__device__ __forceinline__ ushort f2bf(float f) {
  union { float f; unsigned int u; } x; x.f = f;
  unsigned int r = x.u + 0x7fffu + ((x.u >> 16) & 1u);   // RNE
  return (ushort)(r >> 16);
}

// async global->LDS, 16B per lane; LDS dest = wave-uniform base + lane*16
__device__ __forceinline__ void gload16(const ushort* g, ushort* l) {
  __builtin_amdgcn_global_load_lds(
      (__attribute__((address_space(1))) unsigned int*)(g),
      (__attribute__((address_space(3))) unsigned int*)(l), 16, 0, 0);
}

// ---------------------------------------------------------------------------
// prep: blocks 0..8191 = x->bf16; 8192..11263 = W transpose; 11264 = mask scan
__global__ __launch_bounds__(256) void prep(
    const float* __restrict__ x, ushort* __restrict__ xb,
    const float* __restrict__ Wq, const float* __restrict__ Wk,
    const float* __restrict__ Wv, ushort* __restrict__ WT,
    const int* __restrict__ mask, int* __restrict__ flagw) {
  __shared__ float tile[32][33];
  __shared__ int accum[64];
  const int blk = blockIdx.x, t = threadIdx.x;
  if (blk < 8192) {
    int i = blk * 256 + t;
    float4 v = ((const float4*)x)[i];
    ushort4 o;
    o.x = f2bf(v.x); o.y = f2bf(v.y); o.z = f2bf(v.z); o.w = f2bf(v.w);
    ((ushort4*)xb)[i] = o;
  } else if (blk < 11264) {
    int bb = blk - 8192;
    int z = bb >> 10, rem = bb & 1023, db = rem >> 5, nb = rem & 31;
    const float* W = (z == 0) ? Wq : ((z == 1) ? Wk : Wv);
    int tx = t & 31, ty = t >> 5;   // 32 x 8
#pragma unroll
    for (int i = 0; i < 4; i++) {
      int dl = ty + i * 8;
      tile[dl][tx] = W[(size_t)(db * 32 + dl) * 1024 + nb * 32 + tx];
    }
    __syncthreads();
#pragma unroll
    for (int i = 0; i < 4; i++) {
      int nl = ty + i * 8;
      WT[(size_t)(z * 1024 + nb * 32 + nl) * 1024 + db * 32 + tx] = f2bf(tile[tx][nl]);
    }
  } else {
    if (t < 64) accum[t] = 0;
    __syncthreads();
    int p = t >> 2, j = t & 3;          // p = b*16+kt
    int base = p * 128 + j * 32;
    int s = 0;
#pragma unroll
    for (int i = 0; i < 8; i++) {
      int4 v = *(const int4*)(mask + base + i * 4);
      s += v.x + v.y + v.z + v.w;
    }
    atomicAdd(&accum[p], s);
    __syncthreads();
    if (t < 4) {
      int w = 0;
#pragma unroll
      for (int kt = 0; kt < 16; kt++)
        if (accum[t * 16 + kt] != 128) w |= (1 << kt);
      flagw[t] = w;
    }
  }
}

// ---------------------------------------------------------------------------
// fused QKV GEMM, m97 structure + early-issue staging (R8 version, (256,2)).
// blocks 0..1023: mode0 (Q,K: M=8192 N=2048); 1024..1535: mode1 (V^T).
__global__ __launch_bounds__(256, 2) void gemm_qkv(
    const ushort* __restrict__ xb, const ushort* __restrict__ WT,
    const float* __restrict__ bq, const float* __restrict__ bk,
    const float* __restrict__ bv, ushort* __restrict__ Qg,
    ushort* __restrict__ Kg, ushort* __restrict__ VTg) {
  __shared__ __align__(16) ushort As[128 * 64];
  __shared__ __align__(16) ushort Bs[128 * 64];
  const int t = threadIdx.x, wid = t >> 6, lane = t & 63;
  const int blk = blockIdx.x;
  int mode, mb, nb;
  const ushort *A, *B;
  if (blk < 1024) {
    mode = 0;
    int lin2 = (blk & 7) * 128 + (blk >> 3);   // XCD owns 8 mb-panels
    nb = lin2 & 15; mb = lin2 >> 4;
    A = xb; B = WT;
  } else {
    mode = 1;
    int l = blk - 1024;
    int lin2 = (l & 7) * 64 + (l >> 3);        // XCD owns 8 nb-panels
    mb = lin2 & 7; nb = lin2 >> 3;
    A = WT + (size_t)2048 * 1024; B = xb;
  }
  const ushort* Ab = A + (size_t)mb * 128 * 1024;
  const ushort* Bb = B + (size_t)nb * 128 * 1024;
  const int wr = wid >> 1, wc = wid & 1;

  f32x4 acc[4][4] = {};

  const int srow = lane >> 3;              // 0..7 row-in-8
  const int schunk = (lane & 7) ^ srow;    // pre-swizzled source chunk

  // prologue: issue stage(0)
#pragma unroll
  for (int i = 0; i < 4; i++) {
    int blki = i * 4 + wid;
    int row = blki * 8 + srow;
    int ldso = __builtin_amdgcn_readfirstlane(blki * 512);
    gload16(Ab + (size_t)row * 1024 + schunk * 8, As + ldso);
    gload16(Bb + (size_t)row * 1024 + schunk * 8, Bs + ldso);
  }

  for (int kt = 0; kt < 16; ++kt) {
    __syncthreads();                       // (1) stage(kt) arrived

    bf16x8 af[2][4], bf[2][4];
#pragma unroll
    for (int ks = 0; ks < 2; ks++) {
#pragma unroll
      for (int m = 0; m < 4; m++) {
        int row = wr * 64 + m * 16 + (lane & 15);
        int slot = (ks * 4 + (lane >> 4)) ^ (row & 7);
        af[ks][m] = *(const bf16x8*)(As + row * 64 + slot * 8);
      }
#pragma unroll
      for (int n = 0; n < 4; n++) {
        int row = wc * 64 + n * 16 + (lane & 15);
        int slot = (ks * 4 + (lane >> 4)) ^ (row & 7);
        bf[ks][n] = *(const bf16x8*)(Bs + row * 64 + slot * 8);
      }
    }
    __syncthreads();                       // (2) all fragment reads in regs

    if (kt < 15) {
      const int kof = (kt + 1) * 64 + schunk * 8;
#pragma unroll
      for (int i = 0; i < 4; i++) {
        int blki = i * 4 + wid;
        int row = blki * 8 + srow;
        int ldso = __builtin_amdgcn_readfirstlane(blki * 512);
        gload16(Ab + (size_t)row * 1024 + kof, As + ldso);
        gload16(Bb + (size_t)row * 1024 + kof, Bs + ldso);
      }
    }

#pragma unroll
    for (int ks = 0; ks < 2; ks++)
#pragma unroll
      for (int m = 0; m < 4; m++)
#pragma unroll
        for (int n = 0; n < 4; n++)
          acc[m][n] = __builtin_amdgcn_mfma_f32_16x16x32_bf16(
              af[ks][m], bf[ks][n], acc[m][n], 0, 0, 0);
  }

  // epilogue
#pragma unroll
  for (int m = 0; m < 4; m++) {
#pragma unroll
    for (int n = 0; n < 4; n++) {
      if (mode == 0) {
        int col = nb * 128 + wc * 64 + n * 16 + (lane & 15);  // n: [Q|K] 0..2047
        int wq = col >> 10;                                   // 0=Q 1=K
        float bs = wq ? bk[col & 1023] : bq[col & 1023];
        float scale = wq ? 1.0f : (0.125f * LOG2E);           // fold log2e into Q
        ushort* dst = wq ? Kg : Qg;
        int h = (col >> 6) & 15, d = col & 63;
#pragma unroll
        for (int r = 0; r < 4; r++) {
          int row = mb * 128 + wr * 64 + m * 16 + (lane >> 4) * 4 + r;  // b*2048+s
          int b = row >> 11, s = row & 2047;
          float v = (acc[m][n][r] + bs) * scale;
          dst[((size_t)((b << 4) + h) * 2048 + s) * 64 + d] = f2bf(v);
        }
      } else {
        int col = nb * 128 + wc * 64 + n * 16 + (lane & 15);  // m-index: b*2048+s
        int b = col >> 11, s = col & 2047;
#pragma unroll
        for (int r = 0; r < 4; r++) {
          int p = mb * 128 + wr * 64 + m * 16 + (lane >> 4) * 4 + r;  // h*64+d
          float v = acc[m][n][r] + bv[p];
          int h = p >> 6, d = p & 63;
          VTg[((size_t)((b << 4) + h) * 64 + d) * 2048 + s] = f2bf(v);
        }
      }
    }
  }
}

// ---------------------------------------------------------------------------
// Flash attention (R17 body): swapped-operand 32x32 MFMA, single-buffer
// staging (R14 form), T15 att[2] 2-stage pipeline: QK(kb+1) issued before
// finish(kb) so QK MFMAs overlap exp/pack VALU of the previous block.
// Two statically-named P-tiles aA/aB (rule #20: no runtime indexing).
// qf loaded directly from global (no Q-staging prologue / barriers).

#define QK_BLOCK(AOUT, KB)                                                     \
  {                                                                            \
    const ushort* krow = Ks + ((KB) * 16 + prq) * 128;                         \
    __builtin_amdgcn_s_setprio(1);                                             \
    bf16x8 kf0 = *(const bf16x8*)(krow + (((0 + hi) | (halfq << 3)) ^ pr14) * 8); \
    AOUT = __builtin_amdgcn_mfma_f32_32x32x16_bf16(kf0, qf[0], fzero, 0, 0, 0);\
    bf16x8 kf1 = *(const bf16x8*)(krow + (((2 + hi) | (halfq << 3)) ^ pr14) * 8); \
    AOUT = __builtin_amdgcn_mfma_f32_32x32x16_bf16(kf1, qf[1], AOUT, 0, 0, 0); \
    bf16x8 kf2 = *(const bf16x8*)(krow + (((4 + hi) | (halfq << 3)) ^ pr14) * 8); \
    AOUT = __builtin_amdgcn_mfma_f32_32x32x16_bf16(kf2, qf[2], AOUT, 0, 0, 0); \
    bf16x8 kf3 = *(const bf16x8*)(krow + (((6 + hi) | (halfq << 3)) ^ pr14) * 8); \
    AOUT = __builtin_amdgcn_mfma_f32_32x32x16_bf16(kf3, qf[3], AOUT, 0, 0, 0); \
    __builtin_amdgcn_s_setprio(0);                                             \
  }

#define FIN_BLOCK(AIN, KB)                                                     \
  {                                                                            \
    if (msk) {                                                                 \
      _Pragma("unroll")                                                        \
      for (int qd = 0; qd < 4; qd++) {                                         \
        f32x4 ma = *(const f32x4*)(maddv + (KB) * 32 + qd * 8 + hi * 4);       \
        _Pragma("unroll")                                                      \
        for (int rr = 0; rr < 4; rr++) AIN[qd * 4 + rr] += ma[rr];             \
      }                                                                        \
    }                                                                          \
    _Pragma("unroll")                                                          \
    for (int w2 = 0; w2 < 2; w2++) {                                           \
      const int o = w2 * 8;                                                    \
      float e0 = __builtin_amdgcn_exp2f(AIN[o + 0]);                           \
      float e1 = __builtin_amdgcn_exp2f(AIN[o + 1]);                           \
      float e2 = __builtin_amdgcn_exp2f(AIN[o + 2]);                           \
      float e3 = __builtin_amdgcn_exp2f(AIN[o + 3]);                           \
      float e4 = __builtin_amdgcn_exp2f(AIN[o + 4]);                           \
      float e5 = __builtin_amdgcn_exp2f(AIN[o + 5]);                           \
      float e6 = __builtin_amdgcn_exp2f(AIN[o + 6]);                           \
      float e7 = __builtin_amdgcn_exp2f(AIN[o + 7]);                           \
      l0 += e0; l1 += e1; l2 += e2; l3 += e3;                                  \
      l0 += e4; l1 += e5; l2 += e6; l3 += e7;                                  \
      unsigned a0, a1, b0, b1;                                                 \
      asm("v_cvt_pk_bf16_f32 %0, %1, %2" : "=v"(a0) : "v"(e0), "v"(e1));       \
      asm("v_cvt_pk_bf16_f32 %0, %1, %2" : "=v"(a1) : "v"(e2), "v"(e3));       \
      asm("v_cvt_pk_bf16_f32 %0, %1, %2" : "=v"(b0) : "v"(e4), "v"(e5));       \
      asm("v_cvt_pk_bf16_f32 %0, %1, %2" : "=v"(b1) : "v"(e6), "v"(e7));       \
      asm("v_permlane32_swap_b32 %0, %1" : "+v"(a0), "+v"(b0));                \
      asm("v_permlane32_swap_b32 %0, %1" : "+v"(a1), "+v"(b1));                \
      union { unsigned u[4]; bf16x8 v8; } pu;                                  \
      pu.u[0] = a0; pu.u[1] = a1; pu.u[2] = b0; pu.u[3] = b1;                  \
      bf16x8 pf = pu.v8;                                                       \
      const int w = (KB) * 2 + w2;                                             \
      __builtin_amdgcn_s_setprio(1);                                           \
      _Pragma("unroll")                                                        \
      for (int df = 0; df < 2; df++) {                                         \
        int d = df * 32 + l31;                                                 \
        int c = (w * 2 + hi) ^ (d & 15);                                       \
        bf16x8 vf = *(const bf16x8*)(Vs + d * 128 + c * 8);                    \
        cacc[df] = __builtin_amdgcn_mfma_f32_32x32x16_bf16(vf, pf, cacc[df], 0, 0, 0); \
      }                                                                        \
      __builtin_amdgcn_s_setprio(0);                                           \
    }                                                                          \
  }

__global__ __launch_bounds__(256, 2) void attn_kernel(
    const ushort* __restrict__ Qg, const ushort* __restrict__ Kg,
    const ushort* __restrict__ VTg, const int* __restrict__ mask,
    const int* __restrict__ flagw, float* __restrict__ out) {
  __shared__ __align__(16) ushort Ks[128 * 64];   // 16KB; 64 phys rows x 256B
  __shared__ __align__(16) ushort Vs[64 * 128];   // 16KB; rows=d, 4-bit swizzle
  __shared__ float maddv[128];

  const int t = threadIdx.x, wid = t >> 6, lane = t & 63;
  const int l31 = lane & 31, hi = lane >> 5;
  const int lin = blockIdx.x;
  const int lin2 = (lin & 7) * 128 + (lin >> 3);   // bijective XCD chunking
  const int qb = lin2 & 15, bh = lin2 >> 4;
  const int b = bh >> 4, h = bh & 15;
  const ushort* Qbh = Qg + ((size_t)bh * 2048 + qb * 128) * 64;
  const ushort* Kbh = Kg + (size_t)bh * 2048 * 64;
  const ushort* Vbh = VTg + (size_t)bh * 64 * 2048;

  // ---- staging lane constants (pair-interleave inverse map) ----
  const int pr_l = lane >> 4;                 // 0..3 within issue
  const int s_l = lane & 15;

  // ---- fragment-read lane constants ----
  const int prq = l31 >> 1;                   // phys row within 16-row group
  const int halfq = l31 & 1;
  const int pr14 = prq & 15;

  // ---- qf direct from global: Q[q=qb*128+wid*32+l31][d=ds*16+hi*8 ..+7] ----
  bf16x8 qf[4];
  {
    const ushort* qrow = Qbh + (size_t)(wid * 32 + l31) * 64 + hi * 8;
#pragma unroll
    for (int ds = 0; ds < 4; ds++)
      qf[ds] = *(const bf16x8*)(qrow + ds * 16);
  }
  const int fb = flagw[b];            // per-tile mask bits (uniform)

  const f32x16 fzero = {};
  f32x16 cacc[2] = {};
  float l0 = 0.f, l1 = 0.f, l2 = 0.f, l3 = 0.f;  // persistent psum chains

  for (int kt = 0; kt < 16; ++kt) {
    // ---- stage K (pair-interleaved) and VT [64][128], 8 issues/wave ----
#pragma unroll
    for (int i = 0; i < 4; i++) {
      int blki = i * 4 + wid;
      int ldso = __builtin_amdgcn_readfirstlane(blki * 512);
      int pr = blki * 4 + pr_l;
      int sp = s_l ^ (pr & 15);
      gload16(Kbh + (size_t)(kt * 128 + 2 * pr + (sp >> 3)) * 64 + (sp & 7) * 8,
              Ks + ldso);
      int d = blki * 4 + pr_l;
      int cvg = s_l ^ (d & 15);
      gload16(Vbh + (size_t)d * 2048 + kt * 128 + cvg * 8, Vs + ldso);
    }
    const bool msk = ((fb >> kt) & 1) != 0;
    if (msk && t < 128)
      maddv[t] = (1.0f - (float)mask[b * 2048 + kt * 128 + t]) * (-10000.0f * LOG2E);
    __syncthreads();                  // (A) tile kt staged

    // ---- T15 2-stage pipeline: QK(kb+1) in flight while finish(kb) ----
    f32x16 aA, aB;
    QK_BLOCK(aA, 0)
    QK_BLOCK(aB, 1)
    FIN_BLOCK(aA, 0)
    QK_BLOCK(aA, 2)
    FIN_BLOCK(aB, 1)
    QK_BLOCK(aB, 3)
    FIN_BLOCK(aA, 2)
    FIN_BLOCK(aB, 3)

    if (kt < 15) __syncthreads();     // (B) reads done before restage
  }

  // ---- epilogue: l = in-lane chains + cross-hi partner; ctx^T / l ----
  float lrun = (l0 + l1) + (l2 + l3);
  lrun += __shfl_xor(lrun, 32);
  float linv = 1.0f / lrun;
  int qg = qb * 128 + wid * 32 + l31;
  float* op = out + ((size_t)(b * 2048 + qg)) * 1024 + h * 64;
#pragma unroll
  for (int df = 0; df < 2; df++)
#pragma unroll
    for (int qd = 0; qd < 4; qd++) {
      f32x4 v;
      v[0] = cacc[df][qd * 4 + 0] * linv;
      v[1] = cacc[df][qd * 4 + 1] * linv;
      v[2] = cacc[df][qd * 4 + 2] * linv;
      v[3] = cacc[df][qd * 4 + 3] * linv;
      *(f32x4*)(op + df * 32 + qd * 8 + hi * 4) = v;
    }
}

// ---------------------------------------------------------------------------
extern "C" void kernel_launch(void* const* d_in, const int* in_sizes, int n_in,
                              void* d_out, int out_size, void* d_ws, size_t ws_size,
                              hipStream_t stream) {
  const float* x  = (const float*)d_in[0];
  const int* mask = (const int*)d_in[1];
  const float* Wq = (const float*)d_in[2];
  const float* bq = (const float*)d_in[3];
  const float* Wk = (const float*)d_in[4];
  const float* bk = (const float*)d_in[5];
  const float* Wv = (const float*)d_in[6];
  const float* bv = (const float*)d_in[7];
  float* out = (float*)d_out;

  char* ws = (char*)d_ws;
  ushort* xb  = (ushort*)(ws);                                  // 16 MB
  ushort* WT  = (ushort*)(ws + (size_t)16777216);               // 6 MB
  ushort* Qg  = (ushort*)(ws + (size_t)23068672);               // 16 MB
  ushort* Kg  = (ushort*)(ws + (size_t)39845888);               // 16 MB
  ushort* VTg = (ushort*)(ws + (size_t)56623104);               // 16 MB
  int*    flg = (int*)(ws + (size_t)73400320);                  // 16 B

  prep<<<dim3(11265), dim3(256), 0, stream>>>(x, xb, Wq, Wk, Wv, WT, mask, flg);
  gemm_qkv<<<dim3(1536), dim3(256), 0, stream>>>(xb, WT, bq, bk, bv, Qg, Kg, VTg);
  attn_kernel<<<dim3(1024), dim3(256), 0, stream>>>(Qg, Kg, VTg, mask, flg, out);
}